// Round 16
// baseline (138.992 us; speedup 1.0000x reference)
//
#include <hip/hip_runtime.h>
#include <hip/hip_bf16.h>

typedef __attribute__((ext_vector_type(4)))  float f32x4;
typedef __attribute__((ext_vector_type(16))) float f32x16;
typedef __attribute__((ext_vector_type(8)))  short bf16x8;
typedef __attribute__((ext_vector_type(4)))  unsigned u32x4;

#define S_LEN 4096
#define HEAD_D 64
#define WIN 256
#define QBLK 128
#define KVBLK 64
#define VSTR 40   // private V row stride (shorts); b128 reads 16B-aligned
#define QSCALE 0.18033688f   // log2(e)/8 folded into Q; no numerator shift

#define VWBYTES (HEAD_D * VSTR * 2)             // 5120 B per-wave private V buffer
#define LPAR_OFF (8 * VWBYTES)                  // 40960 (o_mrg 32KB overlays this)
#define SMEM_BYTES (LPAR_OFF + 2 * 4 * 32 * 4)  // 41984

static __device__ __forceinline__ unsigned cvt2(float lo, float hi) {
  unsigned r;
  asm("v_cvt_pk_bf16_f32 %0, %1, %2" : "=v"(r) : "v"(lo), "v"(hi));
  return r;
}

// ZERO-BARRIER main loop. Wave (qg,kh) consumes only its own K rows (direct from
// global: the QK A-fragment is a per-lane contiguous row slice -> no LDS, no
// transpose) and its own 32-key V half (private per-wave LDS tile, single buffer:
// DS ops are in-order within a wave, so tile t+1's writes safely follow tile t's
// PV reads with no sync). No cross-wave sharing -> no __syncthreads until epilogue.
__global__ __launch_bounds__(512, 2)   // cap 256 >= demand ~120 (never cap below demand)
void swa_fwd(const float* __restrict__ Q, const float* __restrict__ K,
             const float* __restrict__ V, float* __restrict__ O) {
  __shared__ __attribute__((aligned(16))) char smem[SMEM_BYTES];

  const int tid  = threadIdx.x;
  const int widx = tid >> 6;
  const int lane = tid & 63;
  const int hi   = lane >> 5;
  const int c    = lane & 31;
  const int qg   = widx & 3;
  const int kh   = widx >> 2;
  const int kho  = kh * 32;

  // XCD swizzle: 4 contiguous bh per XCD, qb fastest.
  const int pb  = blockIdx.x;
  const int bh  = (pb & 7) * 4 + ((pb >> 3) >> 5);
  const int qb  = (pb >> 3) & 31;
  const int bq0 = qb * QBLK;
  const int q0w = bq0 + qg * 32;

  const size_t base = (size_t)bh * S_LEN * HEAD_D;
  const float* Qp = Q + base;
  const float* Kp = K + base;
  const float* Vp = V + base;
  float*       Op = O + base;

  const f32x16 Z16 = {0.f,0.f,0.f,0.f,0.f,0.f,0.f,0.f,0.f,0.f,0.f,0.f,0.f,0.f,0.f,0.f};

  // ---- Q B-fragments ----
  bf16x8 aq[4];
  {
    const float* qr = Qp + (size_t)(q0w + c) * HEAD_D + hi * 8;
    #pragma unroll
    for (int ch = 0; ch < 4; ++ch) {
      f32x4 x0 = *(const f32x4*)(qr + ch * 16);
      f32x4 x1 = *(const f32x4*)(qr + ch * 16 + 4);
      u32x4 au;
      au[0] = cvt2(x0[0] * QSCALE, x0[1] * QSCALE);
      au[1] = cvt2(x0[2] * QSCALE, x0[3] * QSCALE);
      au[2] = cvt2(x1[0] * QSCALE, x1[1] * QSCALE);
      au[3] = cvt2(x1[2] * QSCALE, x1[3] * QSCALE);
      aq[ch] = __builtin_bit_cast(bf16x8, au);
    }
  }

  f32x16 acc0 = Z16, acc1 = Z16;
  float lsA = 0.f, lsB = 0.f;

  const int lo   = max(0, bq0 - WIN);
  const int khiB = min(S_LEN, bq0 + QBLK + WIN);
  const int nt   = (khiB - lo) >> 6;

  // ---- per-wave private V tile (single buffer) ----
  short* const vw = (short*)(smem + widx * VWBYTES);
  const short* const vrd = vw + c * VSTR + hi * 8;

  // V staging: lane = dg(0..3 d-group of 16) x kp(0..15 key pair); key' bits2<->3 swap
  const int kp   = lane & 15;
  const int dg   = lane >> 4;
  const int key2 = kp << 1;
  const int kp2p = (key2 & ~12) | ((key2 & 4) << 1) | ((key2 & 8) >> 1);
  short* const vwr = vw + dg * 16 * VSTR + kp2p;

  unsigned kbase = (unsigned)(lo + kho + c) * HEAD_D + hi * 8;     // K row for this lane
  unsigned vbase = (unsigned)(lo + kho + key2) * HEAD_D + dg * 16; // V row pair

  f32x4 kfa[4], kfb[4];          // K fp32 fragment source (transient, QK-time)
  f32x4 va0, va1, va2, va3;      // V row0, 16 d
  f32x4 vb0, vb1, vb2, vb3;      // V row1

  #define LOAD_KF() do {                                          \
    _Pragma("unroll")                                             \
    for (int ch = 0; ch < 4; ++ch) {                              \
      kfa[ch] = *(const f32x4*)(Kp + kbase + ch * 16);            \
      kfb[ch] = *(const f32x4*)(Kp + kbase + ch * 16 + 4);        \
    }                                                             \
  } while (0)

  #define LOAD_VF() do {                                          \
    va0 = *(const f32x4*)(Vp + vbase);                            \
    va1 = *(const f32x4*)(Vp + vbase + 4);                        \
    va2 = *(const f32x4*)(Vp + vbase + 8);                        \
    va3 = *(const f32x4*)(Vp + vbase + 12);                       \
    vb0 = *(const f32x4*)(Vp + vbase + HEAD_D);                   \
    vb1 = *(const f32x4*)(Vp + vbase + HEAD_D + 4);               \
    vb2 = *(const f32x4*)(Vp + vbase + HEAD_D + 8);               \
    vb3 = *(const f32x4*)(Vp + vbase + HEAD_D + 12);              \
  } while (0)

  #define WRITE_VF() do {                                                         \
    _Pragma("unroll")                                                             \
    for (int i = 0; i < 4; ++i) *(unsigned*)&vwr[i * VSTR]        = cvt2(va0[i], vb0[i]); \
    _Pragma("unroll")                                                             \
    for (int i = 0; i < 4; ++i) *(unsigned*)&vwr[(4 + i) * VSTR]  = cvt2(va1[i], vb1[i]); \
    _Pragma("unroll")                                                             \
    for (int i = 0; i < 4; ++i) *(unsigned*)&vwr[(8 + i) * VSTR]  = cvt2(va2[i], vb2[i]); \
    _Pragma("unroll")                                                             \
    for (int i = 0; i < 4; ++i) *(unsigned*)&vwr[(12 + i) * VSTR] = cvt2(va3[i], vb3[i]); \
  } while (0)

  // prologue: stage V tile 0 (private; gated by this wave's liveness)
  {
    const int rel0 = lo + kho - q0w;
    if (rel0 >= -287 && rel0 <= 287) {
      LOAD_VF();
      WRITE_VF();
    }
    vbase += KVBLK * HEAD_D;
  }

  for (int t = 0; t < nt; ++t) {
    const int rel   = lo + (t << 6) + kho - q0w;
    const bool live  = (rel >= -287) && (rel <= 287);        // 32q x 32k band hit
    const bool liveN = (t + 1 < nt) && (rel + 64 >= -287) && (rel + 64 <= 287);

    f32x16 s = Z16;
    if (live) {
      LOAD_KF();                       // K for THIS tile, straight from L1/L2
      __builtin_amdgcn_s_setprio(1);
      #pragma unroll
      for (int ch = 0; ch < 4; ++ch) {
        u32x4 au;
        au[0] = cvt2(kfa[ch][0], kfa[ch][1]);
        au[1] = cvt2(kfa[ch][2], kfa[ch][3]);
        au[2] = cvt2(kfb[ch][0], kfb[ch][1]);
        au[3] = cvt2(kfb[ch][2], kfb[ch][3]);
        const bf16x8 akf = __builtin_bit_cast(bf16x8, au);
        s = __builtin_amdgcn_mfma_f32_32x32x16_bf16(akf, aq[ch], s, 0, 0, 0);
      }
      __builtin_amdgcn_s_setprio(0);
    }
    if (liveN) LOAD_VF();              // V for t+1; latency hides under SM + PV

    if (live) {
      // ---- softmax numerator, no shift; reg g = key (g&3)+8*(g>>2)+4hi, q = c ----
      if (rel >= -224 && rel <= 224) {
        #pragma unroll
        for (int g = 0; g < 16; g += 2) {
          const float p0 = __builtin_amdgcn_exp2f(s[g]);
          const float p1 = __builtin_amdgcn_exp2f(s[g + 1]);
          s[g] = p0; s[g + 1] = p1; lsA += p0; lsB += p1;
        }
      } else {
        const int bm = rel + 4 * hi - c + WIN;
        #pragma unroll
        for (int g = 0; g < 16; ++g) {
          const int ro = (g & 3) + 8 * (g >> 2);
          const float p = ((unsigned)(bm + ro) <= 2u * WIN)
                            ? __builtin_amdgcn_exp2f(s[g]) : 0.f;
          s[g] = p; if (g & 1) lsB += p; else lsA += p;
        }
      }
      // ---- PV from private V (register-P bijection) ----
      __builtin_amdgcn_s_setprio(1);
      #pragma unroll
      for (int kt = 0; kt < 2; ++kt) {
        u32x4 pau;
        #pragma unroll
        for (int p2 = 0; p2 < 4; ++p2)
          pau[p2] = cvt2(s[kt * 8 + 2 * p2], s[kt * 8 + 2 * p2 + 1]);
        const bf16x8 pa = __builtin_bit_cast(bf16x8, pau);
        bf16x8 bv0 = *(const bf16x8*)&vrd[kt * 16];
        acc0 = __builtin_amdgcn_mfma_f32_32x32x16_bf16(pa, bv0, acc0, 0, 0, 0);
        bf16x8 bv1 = *(const bf16x8*)&vrd[kt * 16 + 32 * VSTR];
        acc1 = __builtin_amdgcn_mfma_f32_32x32x16_bf16(pa, bv1, acc1, 0, 0, 0);
      }
      __builtin_amdgcn_s_setprio(0);
    }

    if (liveN) WRITE_VF();             // overwrite own buffer; DS in-order after PV reads
    kbase += KVBLK * HEAD_D;
    vbase += KVBLK * HEAD_D;
  }

  // ---- epilogue: merge kh halves; overlay on dead private-V LDS ----
  float lsum = lsA + lsB;
  lsum += __shfl_xor(lsum, 32);
  __syncthreads();                               // all private PV reads done -> overlay safe
  float* o_mrg = (float*)smem;                   // [4][32][64] f32 = 32 KB
  float* l_par = (float*)(smem + LPAR_OFF);      // [2 kh][4 qg][32]
  if (hi == 0) l_par[(kh * 4 + qg) * 32 + c] = lsum;
  if (kh == 0) {
    #pragma unroll
    for (int g = 0; g < 16; ++g) {
      const int qrow = (g & 3) + 8 * (g >> 2) + 4 * hi;
      o_mrg[(qg * 32 + qrow) * HEAD_D + c]      = acc0[g];
      o_mrg[(qg * 32 + qrow) * HEAD_D + 32 + c] = acc1[g];
    }
  }
  __syncthreads();
  if (kh == 1) {
    if (hi == 0) l_par[qg * 32 + c] = 1.0f / (l_par[qg * 32 + c] + l_par[(4 + qg) * 32 + c]);
    __asm__ volatile("s_waitcnt lgkmcnt(0)" ::: "memory");   // same-wave write->read
    __builtin_amdgcn_sched_barrier(0);
    #pragma unroll
    for (int g = 0; g < 16; ++g) {
      const int qrow = (g & 3) + 8 * (g >> 2) + 4 * hi;
      const float iv = l_par[qg * 32 + qrow];
      float* orow = Op + (size_t)(q0w + qrow) * HEAD_D;
      orow[c]      = (o_mrg[(qg * 32 + qrow) * HEAD_D + c]      + acc0[g]) * iv;
      orow[32 + c] = (o_mrg[(qg * 32 + qrow) * HEAD_D + 32 + c] + acc1[g]) * iv;
    }
  }
}

extern "C" void kernel_launch(void* const* d_in, const int* in_sizes, int n_in,
                              void* d_out, int out_size, void* d_ws, size_t ws_size,
                              hipStream_t stream) {
  const float* q = (const float*)d_in[0];
  const float* k = (const float*)d_in[1];
  const float* v = (const float*)d_in[2];
  float* o = (float*)d_out;
  const int blocks = 2 * 16 * (S_LEN / QBLK);  // 1024
  swa_fwd<<<dim3(blocks), dim3(512), 0, stream>>>(q, k, v, o);
}

// Round 17
// 47.035 us; speedup vs baseline: 2.9551x; 2.9551x over previous
//
#include <hip/hip_runtime.h>
#include <hip/hip_bf16.h>

typedef __attribute__((ext_vector_type(4)))  float f32x4;
typedef __attribute__((ext_vector_type(16))) float f32x16;
typedef __attribute__((ext_vector_type(8)))  short bf16x8;
typedef __attribute__((ext_vector_type(4)))  unsigned u32x4;

#define S_LEN 4096
#define HEAD_D 64
#define WIN 256
#define QBLK 128
#define KVBLK 64
#define KSTR 72   // k_lds row stride (shorts)
#define VSTR 72   // vt_lds row stride (shorts), [d][key'] key' = key with bits2<->3 swapped
#define QSCALE 0.18033688f   // log2(e)/8 folded into Q; no numerator shift

#define KBYTES (KVBLK * KSTR * 2)    // 9216 B per K buffer
#define VBYTES (HEAD_D * VSTR * 2)   // 9216 B per V buffer
#define KHALF  (KBYTES / 2)          // buffer stride in shorts (4608)
#define VHALF  (VBYTES / 2)
#define LPAR_OFF (2 * KBYTES + 2 * VBYTES)          // 36864
#define SMEM_BYTES (LPAR_OFF + 2 * 4 * 32 * 4)      // 37888

static __device__ __forceinline__ unsigned cvt2(float lo, float hi) {
  unsigned r;
  asm("v_cvt_pk_bf16_f32 %0, %1, %2" : "=v"(r) : "v"(lo), "v"(hi));
  return r;
}

// Publish barrier: drains LDS only; in-flight global prefetch loads ride across.
#define PUB_BARRIER() do {                              \
    __builtin_amdgcn_sched_barrier(0);                  \
    asm volatile("s_waitcnt lgkmcnt(0)" ::: "memory");  \
    __builtin_amdgcn_s_barrier();                       \
    __builtin_amdgcn_sched_barrier(0);                  \
  } while (0)

__global__ __launch_bounds__(512, 4)   // R11-proven: VGPR 60, no spill
void swa_fwd(const float* __restrict__ Q, const float* __restrict__ K,
             const float* __restrict__ V, float* __restrict__ O) {
  __shared__ __attribute__((aligned(16))) char smem[SMEM_BYTES];

  const int tid  = threadIdx.x;
  const int widx = tid >> 6;
  const int lane = tid & 63;
  const int hi   = lane >> 5;
  const int c    = lane & 31;
  const int qg   = widx & 3;
  const int kh   = widx >> 2;
  const int kho  = kh * 32;

  // XCD swizzle: 4 contiguous bh per XCD, qb fastest.
  const int pb  = blockIdx.x;
  const int bh  = (pb & 7) * 4 + ((pb >> 3) >> 5);
  const int qb  = (pb >> 3) & 31;
  const int bq0 = qb * QBLK;
  const int q0w = bq0 + qg * 32;

  const size_t base = (size_t)bh * S_LEN * HEAD_D;
  const float* Qp = Q + base;
  const float* Kp = K + base;
  const float* Vp = V + base;
  float*       Op = O + base;

  const f32x16 Z16 = {0.f,0.f,0.f,0.f,0.f,0.f,0.f,0.f,0.f,0.f,0.f,0.f,0.f,0.f,0.f,0.f};

  // ---- Q B-fragments ----
  bf16x8 aq[4];
  {
    const float* qr = Qp + (size_t)(q0w + c) * HEAD_D + hi * 8;
    #pragma unroll
    for (int ch = 0; ch < 4; ++ch) {
      f32x4 x0 = *(const f32x4*)(qr + ch * 16);
      f32x4 x1 = *(const f32x4*)(qr + ch * 16 + 4);
      u32x4 au;
      au[0] = cvt2(x0[0] * QSCALE, x0[1] * QSCALE);
      au[1] = cvt2(x0[2] * QSCALE, x0[3] * QSCALE);
      au[2] = cvt2(x1[0] * QSCALE, x1[1] * QSCALE);
      au[3] = cvt2(x1[2] * QSCALE, x1[3] * QSCALE);
      aq[ch] = __builtin_bit_cast(bf16x8, au);
    }
  }

  f32x16 acc0 = Z16, acc1 = Z16;
  float lsA = 0.f, lsB = 0.f;

  const int lo   = max(0, bq0 - WIN);
  const int khiB = min(S_LEN, bq0 + QBLK + WIN);
  const int nt   = (khiB - lo) >> 6;   // in {6,8,10}: always even -> clean 2-unroll

  // staging lane assignment
  const int krow  = tid >> 3;
  const int kc8   = (tid & 7) << 3;
  const int key2  = (tid & 31) << 1;
  const int key2p = (key2 & ~12) | ((key2 & 4) << 1) | ((key2 & 8) >> 1);
  const int vd4   = (tid >> 5) << 2;

  // hoisted LDS bases
  short* const ksh = (short*)smem;
  short* const vsh = (short*)(smem + 2 * KBYTES);
  const short* const krd = ksh + (kho + c) * KSTR + hi * 8;     // QK reads
  const short* const vrd = vsh + c * VSTR + kho + hi * 8;       // PV reads
  short* const kwr = ksh + krow * KSTR + kc8;                   // K stage write
  short* const vwr = vsh + vd4 * VSTR + key2p;                  // V stage writes

  unsigned koff = (unsigned)(lo + krow) * HEAD_D + kc8;
  unsigned voff = (unsigned)(lo + key2) * HEAD_D + vd4;

  f32x4 ka0, ka1, va0, va1;
  #define LOAD_TILE() do {                          \
    ka0 = *(const f32x4*)(Kp + koff);               \
    ka1 = *(const f32x4*)(Kp + koff + 4);           \
    va0 = *(const f32x4*)(Vp + voff);               \
    va1 = *(const f32x4*)(Vp + voff + HEAD_D);      \
    koff += KVBLK * HEAD_D;                         \
    voff += KVBLK * HEAD_D;                         \
  } while (0)

  #define STAGE_TO(BUF) do {                                        \
    u32x4 kw;                                                       \
    kw[0] = cvt2(ka0[0], ka0[1]);                                   \
    kw[1] = cvt2(ka0[2], ka0[3]);                                   \
    kw[2] = cvt2(ka1[0], ka1[1]);                                   \
    kw[3] = cvt2(ka1[2], ka1[3]);                                   \
    *(u32x4*)&kwr[(BUF) * KHALF] = kw;                              \
    _Pragma("unroll")                                               \
    for (int j = 0; j < 4; ++j)                                     \
      *(unsigned*)&vwr[(BUF) * VHALF + j * VSTR] = cvt2(va0[j], va1[j]); \
  } while (0)

  // Tile body (R11 order) + wave-uniform dead-subtile skip:
  //   [QK if live] -> STAGE(t+1) -> LOAD(t+2) -> [SM -> PV if live] -> barrier
  // live iff the 32q x 32k sub-tile intersects the band: rel in [-287, 287].
  #define TILE_BODY(T, BUF) do {                                              \
    const int rel_ = lo + ((T) << 6) + kho - q0w;                             \
    const bool live_ = (rel_ >= -287) && (rel_ <= 287);                       \
    f32x16 s = Z16;                                                           \
    if (live_) {                                                              \
      __builtin_amdgcn_s_setprio(1);                                          \
      _Pragma("unroll")                                                       \
      for (int ch = 0; ch < 4; ++ch) {                                        \
        bf16x8 akf = *(const bf16x8*)&krd[(BUF) * KHALF + ch * 16];           \
        s = __builtin_amdgcn_mfma_f32_32x32x16_bf16(akf, aq[ch], s, 0, 0, 0); \
      }                                                                       \
      __builtin_amdgcn_s_setprio(0);                                          \
    }                                                                         \
    if ((T) + 1 < nt) {                                                       \
      STAGE_TO((BUF) ^ 1);                                                    \
      if ((T) + 2 < nt) LOAD_TILE();                                          \
    }                                                                         \
    if (live_) {                                                              \
      if (rel_ >= -224 && rel_ <= 224) {                                      \
        _Pragma("unroll")                                                     \
        for (int g = 0; g < 16; g += 2) {                                     \
          const float p0 = __builtin_amdgcn_exp2f(s[g]);                      \
          const float p1 = __builtin_amdgcn_exp2f(s[g + 1]);                  \
          s[g] = p0; s[g + 1] = p1; lsA += p0; lsB += p1;                     \
        }                                                                     \
      } else {                                                                \
        const int bm_ = rel_ + 4 * hi - c + WIN;                              \
        _Pragma("unroll")                                                     \
        for (int g = 0; g < 16; ++g) {                                        \
          const int ro_ = (g & 3) + 8 * (g >> 2);                             \
          const float p = ((unsigned)(bm_ + ro_) <= 2u * WIN)                 \
                            ? __builtin_amdgcn_exp2f(s[g]) : 0.f;             \
          s[g] = p; if (g & 1) lsB += p; else lsA += p;                       \
        }                                                                     \
      }                                                                       \
      __builtin_amdgcn_s_setprio(1);                                          \
      _Pragma("unroll")                                                       \
      for (int kt = 0; kt < 2; ++kt) {                                        \
        u32x4 pau;                                                            \
        _Pragma("unroll")                                                     \
        for (int p2 = 0; p2 < 4; ++p2)                                        \
          pau[p2] = cvt2(s[kt * 8 + 2 * p2], s[kt * 8 + 2 * p2 + 1]);         \
        const bf16x8 pa = __builtin_bit_cast(bf16x8, pau);                    \
        bf16x8 bv0 = *(const bf16x8*)&vrd[(BUF) * VHALF + kt * 16];           \
        acc0 = __builtin_amdgcn_mfma_f32_32x32x16_bf16(pa, bv0, acc0, 0,0,0); \
        bf16x8 bv1 = *(const bf16x8*)&vrd[(BUF) * VHALF + kt * 16 + 32 * VSTR]; \
        acc1 = __builtin_amdgcn_mfma_f32_32x32x16_bf16(pa, bv1, acc1, 0,0,0); \
      }                                                                       \
      __builtin_amdgcn_s_setprio(0);                                          \
    }                                                                         \
    if ((T) + 1 < nt) PUB_BARRIER();                                          \
  } while (0)

  // prologue: stage tile 0 into buf 0, prefetch tile 1 (loads ride across barrier)
  LOAD_TILE();
  STAGE_TO(0);
  LOAD_TILE();
  PUB_BARRIER();

  for (int t = 0; t < nt; t += 2) {   // nt even: buffer index is compile-time
    TILE_BODY(t, 0);
    TILE_BODY(t + 1, 1);
  }

  // ---- epilogue: merge key halves; overlay on dead K/V LDS ----
  float lsum = lsA + lsB;
  lsum += __shfl_xor(lsum, 32);
  __syncthreads();
  float* o_mrg = (float*)smem;                   // [4][32][64]
  float* l_par = (float*)(smem + LPAR_OFF);      // [2][4][32]
  if (hi == 0) l_par[(kh * 4 + qg) * 32 + c] = lsum;
  if (kh == 0) {
    #pragma unroll
    for (int g = 0; g < 16; ++g) {
      const int qrow = (g & 3) + 8 * (g >> 2) + 4 * hi;
      o_mrg[(qg * 32 + qrow) * HEAD_D + c]      = acc0[g];
      o_mrg[(qg * 32 + qrow) * HEAD_D + 32 + c] = acc1[g];
    }
  }
  __syncthreads();
  if (kh == 1) {
    if (hi == 0) l_par[qg * 32 + c] = 1.0f / (l_par[qg * 32 + c] + l_par[(4 + qg) * 32 + c]);
    __asm__ volatile("s_waitcnt lgkmcnt(0)" ::: "memory");
    __builtin_amdgcn_sched_barrier(0);
    #pragma unroll
    for (int g = 0; g < 16; ++g) {
      const int qrow = (g & 3) + 8 * (g >> 2) + 4 * hi;
      const float iv = l_par[qg * 32 + qrow];
      float* orow = Op + (size_t)(q0w + qrow) * HEAD_D;
      orow[c]      = (o_mrg[(qg * 32 + qrow) * HEAD_D + c]      + acc0[g]) * iv;
      orow[32 + c] = (o_mrg[(qg * 32 + qrow) * HEAD_D + 32 + c] + acc1[g]) * iv;
    }
  }
}

extern "C" void kernel_launch(void* const* d_in, const int* in_sizes, int n_in,
                              void* d_out, int out_size, void* d_ws, size_t ws_size,
                              hipStream_t stream) {
  const float* q = (const float*)d_in[0];
  const float* k = (const float*)d_in[1];
  const float* v = (const float*)d_in[2];
  float* o = (float*)d_out;
  const int blocks = 2 * 16 * (S_LEN / QBLK);  // 1024
  swa_fwd<<<dim3(blocks), dim3(512), 0, stream>>>(q, k, v, o);
}